// Round 5
// baseline (312.430 us; speedup 1.0000x reference)
//
#include <hip/hip_runtime.h>
#include <hip/hip_bf16.h>

typedef __attribute__((ext_vector_type(8))) short short8;
typedef __attribute__((ext_vector_type(4))) float floatx4;

#define NRES 700
#define DDIM 1024
#define HID 1024
// M = 89600, K = 1024, N = 1024

__device__ __forceinline__ unsigned short f2bf(float f) {
  unsigned u = __float_as_uint(f);
  u = (u + 0x7FFFu + ((u >> 16) & 1u)) >> 16;  // RNE
  return (unsigned short)u;
}

__device__ __forceinline__ void async_copy16(void* lds, const void* g) {
  __builtin_amdgcn_global_load_lds(
      (const __attribute__((address_space(1))) unsigned*)g,
      (__attribute__((address_space(3))) unsigned*)lds, 16, 0, 0);
}

// packed fp32x2 -> bf16x2 (RNE); compiler emits v_cvt_pk_bf16_f32
__device__ __forceinline__ unsigned cvtpk(float lo, float hi) {
  float2 f2; f2.x = lo; f2.y = hi;
  __hip_bfloat162 h = __float22bfloat162_rn(f2);
  return *reinterpret_cast<unsigned*>(&h);
}

// W1 [d][h] fp32 -> W1T [h][d] bf16
__global__ void transpose_w1_kernel(const float* __restrict__ W1,
                                    unsigned short* __restrict__ W1T) {
  __shared__ float tile[32][33];
  int bx = blockIdx.x, by = blockIdx.y;
  int tx = threadIdx.x, ty = threadIdx.y;
#pragma unroll
  for (int i = 0; i < 32; i += 8)
    tile[ty + i][tx] = W1[(size_t)(by * 32 + ty + i) * HID + bx * 32 + tx];
  __syncthreads();
#pragma unroll
  for (int i = 0; i < 32; i += 8)
    W1T[(size_t)(bx * 32 + ty + i) * DDIM + by * 32 + tx] = f2bf(tile[tx][ty + i]);
}

__global__ void init_out_kernel(float* __restrict__ out, const float* __restrict__ b2, int n) {
  int i = blockIdx.x * blockDim.x + threadIdx.x;
  if (i < n) out[i] = b2[0];
}

// Fused single-pass MLP: A stays fp32 in HBM, staged fp32 via global_load_lds,
// converted to bf16 on the fragment-read path (v_cvt_pk_bf16_f32).
// 128x128 tile, BK=64, 4 waves (2x2), m97 2-barrier structure.
// A LDS: rows of 16x16B chunks, involution chunk^=(row&15) on source & read.
// B LDS: rows of 8x16B chunks, involution chunk^=(row&7) (round-4 proven).
__launch_bounds__(256, 3)
__global__ void fused_mlp_kernel(const float* __restrict__ A,
                                 const unsigned short* __restrict__ W1T,
                                 const float* __restrict__ b1,
                                 const float* __restrict__ W2,
                                 float* __restrict__ out) {
  __shared__ __align__(16) float As[128 * 64];           // 32 KB fp32
  __shared__ __align__(16) unsigned short Bs[128 * 64];  // 16 KB bf16

  int bid = blockIdx.x;
  // bijective XCD swizzle: 5600 = 8 XCDs * 700
  int w = (bid & 7) * 700 + (bid >> 3);
  int blk_m = w >> 3;  // residue r: 0..699
  int blk_n = w & 7;   // 0..7
  int m0 = blk_m * 128;
  int n0 = blk_n * 128;

  int t = threadIdx.x;
  int lane = t & 63;
  int wid = t >> 6;
  int wm = wid >> 1, wn = wid & 1;       // 2x2 waves, 64x64 each
  int lrow = lane & 15, lk = lane >> 4;  // fragment decomposition

  floatx4 acc[4][4];
#pragma unroll
  for (int i = 0; i < 4; ++i)
#pragma unroll
    for (int j = 0; j < 4; ++j) acc[i][j] = (floatx4)(0.f);

  for (int kt = 0; kt < 16; ++kt) {
    int k0 = kt * 64;
    // ---- A: 8 DMA copies/thread (fp32, 16 chunks of 16B per row) ----
#pragma unroll
    for (int p = 0; p < 8; ++p) {
      int dbase = p * 256 + wid * 64;  // wave-uniform chunk base
      int d = dbase + lane;
      int row = d >> 4, slot = d & 15;
      int sc = slot ^ (row & 15);  // inverse-swizzled source chunk
      async_copy16(&As[dbase * 4], A + (size_t)(m0 + row) * DDIM + k0 + sc * 4);
    }
    // ---- B: 4 DMA copies/thread (bf16, 8 chunks per row) ----
#pragma unroll
    for (int p = 0; p < 4; ++p) {
      int cbase = p * 256 + wid * 64;
      int c = cbase + lane;
      int row = c >> 3, slot = c & 7;
      int sc = slot ^ (row & 7);
      async_copy16(&Bs[cbase * 8], W1T + (size_t)(n0 + row) * DDIM + k0 + sc * 8);
    }
    __syncthreads();  // drains DMA (vmcnt 0) before reads

    // ---- compute: 2 k-slices of 32, 16 MFMA each ----
#pragma unroll
    for (int ks = 0; ks < 2; ++ks) {
      short8 af[4], bf[4];
#pragma unroll
      for (int f = 0; f < 4; ++f) {
        int arow = wm * 64 + f * 16 + lrow;
        int j = ks * 4 + lk;
        const float* ap = &As[arow * 64];
        // LDS[row][slot] holds global chunk slot^(row&15); row&15 == lrow here
        float4 f0 = *(const float4*)(ap + (((2 * j)) ^ lrow) * 4);
        float4 f1 = *(const float4*)(ap + (((2 * j) | 1) ^ lrow) * 4);
        union { unsigned u[4]; short8 s; } cv;
        cv.u[0] = cvtpk(f0.x, f0.y);
        cv.u[1] = cvtpk(f0.z, f0.w);
        cv.u[2] = cvtpk(f1.x, f1.y);
        cv.u[3] = cvtpk(f1.z, f1.w);
        af[f] = cv.s;
        int brow = wn * 64 + f * 16 + lrow;
        int bc = j ^ (brow & 7);
        bf[f] = *(const short8*)(&Bs[brow * 64 + bc * 8]);
      }
#pragma unroll
      for (int fm = 0; fm < 4; ++fm)
#pragma unroll
        for (int fn = 0; fn < 4; ++fn)
          acc[fm][fn] = __builtin_amdgcn_mfma_f32_16x16x32_bf16(af[fm], bf[fn], acc[fm][fn], 0, 0, 0);
    }
    __syncthreads();  // protect LDS before next stage
  }

  // ---- epilogue: +b1, relu, dot W2, shfl-reduce 16 cols, atomicAdd ----
  float w2v[4], b1v[4];
#pragma unroll
  for (int fn = 0; fn < 4; ++fn) {
    int col = n0 + wn * 64 + fn * 16 + lrow;
    w2v[fn] = W2[col];
    b1v[fn] = b1[col];
  }
#pragma unroll
  for (int fm = 0; fm < 4; ++fm) {
#pragma unroll
    for (int j = 0; j < 4; ++j) {
      float p = 0.f;
#pragma unroll
      for (int fn = 0; fn < 4; ++fn) {
        float h = acc[fm][fn][j] + b1v[fn];
        h = fmaxf(h, 0.f);
        p += h * w2v[fn];
      }
      p += __shfl_xor(p, 1);
      p += __shfl_xor(p, 2);
      p += __shfl_xor(p, 4);
      p += __shfl_xor(p, 8);
      if ((lane & 15) == 0) {
        int row = wm * 64 + fm * 16 + (lk << 2) + j;  // local row = batch b
        atomicAdd(&out[row * NRES + blk_m], p);       // out[b*700 + r]
      }
    }
  }
}

extern "C" void kernel_launch(void* const* d_in, const int* in_sizes, int n_in,
                              void* d_out, int out_size, void* d_ws, size_t ws_size,
                              hipStream_t stream) {
  const float* s_s = (const float*)d_in[0];  // [700,128,1024] fp32
  const float* W1 = (const float*)d_in[1];   // [1024,1024]
  const float* b1 = (const float*)d_in[2];   // [1024]
  const float* W2 = (const float*)d_in[3];   // [1024,1]
  const float* b2 = (const float*)d_in[4];   // [1]
  float* out = (float*)d_out;                // [128,700,1] fp32

  unsigned short* W1T = (unsigned short*)d_ws;  // 2 MB bf16

  dim3 tb(32, 8);
  dim3 tg(HID / 32, DDIM / 32);
  transpose_w1_kernel<<<tg, tb, 0, stream>>>(W1, W1T);

  init_out_kernel<<<(out_size + 255) / 256, 256, 0, stream>>>(out, b2, out_size);

  fused_mlp_kernel<<<NRES * 8, 256, 0, stream>>>(s_s, W1T, b1, W2, out);
}